// Round 3
// baseline (379.450 us; speedup 1.0000x reference)
//
#include <hip/hip_runtime.h>

#define N_IMGS 8
#define C 256
#define H 128
#define W 128
#define R 1024
#define HOUT 14
#define WOUT 14
#define NPOS 196          // HOUT*WOUT
#define HW (H * W)        // 16384
#define IMG_ELEMS (C * HW)

// ---------------------------------------------------------------------------
// Kernel 1: NCHW -> NHWC transpose (per image: (C, HW) -> (HW, C))
// 32x32 tile via LDS, +1 pad to kill bank conflicts. Coalesced both sides.
// Measured at HBM roofline (~42 us for 268 MB) -- unchanged.
// ---------------------------------------------------------------------------
__global__ __launch_bounds__(256) void transpose_nchw_nhwc(
    const float* __restrict__ in, float* __restrict__ out) {
  __shared__ float tile[32][33];
  const int n   = blockIdx.z;
  const int hw0 = blockIdx.x * 32;
  const int c0  = blockIdx.y * 32;
  const float* inp = in + (size_t)n * IMG_ELEMS;
  float* outp      = out + (size_t)n * IMG_ELEMS;
  const int tx = threadIdx.x;  // 0..31
  const int ty = threadIdx.y;  // 0..7

#pragma unroll
  for (int i = 0; i < 4; ++i) {
    int cc = ty + i * 8;
    tile[cc][tx] = inp[(size_t)(c0 + cc) * HW + hw0 + tx];
  }
  __syncthreads();
#pragma unroll
  for (int i = 0; i < 4; ++i) {
    int hh = ty + i * 8;
    outp[(size_t)(hw0 + hh) * C + c0 + tx] = tile[tx][hh];
  }
}

// ---------------------------------------------------------------------------
// Kernel 2: RoI Align.
// Grid = 2*R blocks of 512 threads; roi r = blockIdx.x>>1. Thread -> channel
// c = tid&255, position-quarter pg = (half<<1)|(tid>>8); pg0..2 own 48
// positions, pg3 owns 52. Per 8-position chunk ALL 32 gather loads are issued
// before any FMA (va/vb/vc/vd arrays), giving ~8KB/wave of loads in flight.
// __launch_bounds__(512,4): 128-VGPR budget so the compiler can actually
// keep them in flight (round-2's (512,8) capped VGPR=32 and serialized).
// Offsets are pre-scaled by C at setup so per-corner addressing is one add.
// ---------------------------------------------------------------------------
template <bool NHWC>
__global__ __launch_bounds__(512, 4) void roi_align_kernel(
    const float* __restrict__ feats, const float* __restrict__ rois,
    float* __restrict__ out) {
  __shared__ int4   s_off[NPOS];   // element offsets; NHWC: o*C, NCHW: o
  __shared__ float4 s_w[NPOS];

  const int r    = blockIdx.x >> 1;
  const int half = blockIdx.x & 1;
  const int tid  = threadIdx.x;
  const int c    = tid & 255;
  const int pg   = (half << 1) | (tid >> 8);

  const float bf = rois[r * 5 + 0];
  const float x1 = rois[r * 5 + 1];
  const float y1 = rois[r * 5 + 2];
  const float x2 = rois[r * 5 + 3];
  const float y2 = rois[r * 5 + 4];
  const int   n  = (int)bf;

  if (tid < NPOS) {
    const int ph = tid / WOUT;
    const int pw = tid - ph * WOUT;
    const float px_rel = (pw + 0.5f) / (float)WOUT;
    const float py_rel = (ph + 0.5f) / (float)HOUT;
    const float x_abs = px_rel * (x2 - x1) + x1;
    const float y_abs = py_rel * (y2 - y1) + y1;
    // rx = x_abs / W * 0.25 ; px = rx * W - 0.5  ==  x_abs * 0.25 - 0.5
    const float px = x_abs * 0.25f - 0.5f;
    const float py = y_abs * 0.25f - 0.5f;
    const float x0f = floorf(px);
    const float y0f = floorf(py);
    const float lx = px - x0f, ly = py - y0f;
    const float hx = 1.0f - lx, hy = 1.0f - ly;
    const int ix0 = (int)x0f;
    const int iy0 = (int)y0f;
    const int ix1 = ix0 + 1;
    const int iy1 = iy0 + 1;
    // Reference pads with zeros and clips into the pad -> OOB corners
    // contribute exactly 0. Reproduce by zeroing the weight.
    const bool vx0 = (ix0 >= 0) && (ix0 < W);
    const bool vx1 = (ix1 >= 0) && (ix1 < W);
    const bool vy0 = (iy0 >= 0) && (iy0 < H);
    const bool vy1 = (iy1 >= 0) && (iy1 < H);
    const int cx0 = min(max(ix0, 0), W - 1);
    const int cx1 = min(max(ix1, 0), W - 1);
    const int cy0 = min(max(iy0, 0), H - 1);
    const int cy1 = min(max(iy1, 0), H - 1);
    const int scale = NHWC ? C : 1;
    int4 o;
    o.x = (cy0 * W + cx0) * scale;
    o.y = (cy1 * W + cx0) * scale;
    o.z = (cy0 * W + cx1) * scale;
    o.w = (cy1 * W + cx1) * scale;
    float4 w4;
    w4.x = (vx0 && vy0) ? hx * hy : 0.0f;
    w4.y = (vx0 && vy1) ? hx * ly : 0.0f;
    w4.z = (vx1 && vy0) ? lx * hy : 0.0f;
    w4.w = (vx1 && vy1) ? lx * ly : 0.0f;
    s_off[tid] = o;
    s_w[tid]   = w4;
  }
  __syncthreads();

  // NHWC: base pre-offset by channel, gather = base[o] with o pre-scaled.
  // NCHW fallback: base = channel plane, gather = base[o].
  const float* base = NHWC ? (feats + (size_t)n * IMG_ELEMS + c)
                           : (feats + (size_t)n * IMG_ELEMS + (size_t)c * HW);
  float* outp = out + ((size_t)r * C + c) * NPOS;

  const int p_begin = pg * 48;
  const int p_end   = (pg == 3) ? NPOS : p_begin + 48;  // 48,48,48,52

  int p0 = p_begin;
#pragma unroll 1
  for (; p0 + 8 <= p_end; p0 += 8) {
    float  va[8], vb[8], vc[8], vd[8];
    float4 wt[8];
    // Phase 1: issue all 32 gathers (plus metadata reads) before consuming.
#pragma unroll
    for (int k = 0; k < 8; ++k) {
      const int4 o = s_off[p0 + k];
      wt[k] = s_w[p0 + k];
      va[k] = base[o.x];
      vb[k] = base[o.y];
      vc[k] = base[o.z];
      vd[k] = base[o.w];
    }
    // Phase 2: combine.
    float res[8];
#pragma unroll
    for (int k = 0; k < 8; ++k) {
      res[k] = va[k] * wt[k].x + vb[k] * wt[k].y + vc[k] * wt[k].z +
               vd[k] * wt[k].w;
    }
    *reinterpret_cast<float4*>(outp + p0) =
        make_float4(res[0], res[1], res[2], res[3]);
    *reinterpret_cast<float4*>(outp + p0 + 4) =
        make_float4(res[4], res[5], res[6], res[7]);
  }
  if (p0 < p_end) {  // tail of 4 (pg==3 only)
    float  va[4], vb[4], vc[4], vd[4];
    float4 wt[4];
#pragma unroll
    for (int k = 0; k < 4; ++k) {
      const int4 o = s_off[p0 + k];
      wt[k] = s_w[p0 + k];
      va[k] = base[o.x];
      vb[k] = base[o.y];
      vc[k] = base[o.z];
      vd[k] = base[o.w];
    }
    float res[4];
#pragma unroll
    for (int k = 0; k < 4; ++k) {
      res[k] = va[k] * wt[k].x + vb[k] * wt[k].y + vc[k] * wt[k].z +
               vd[k] * wt[k].w;
    }
    *reinterpret_cast<float4*>(outp + p0) =
        make_float4(res[0], res[1], res[2], res[3]);
  }
}

extern "C" void kernel_launch(void* const* d_in, const int* in_sizes, int n_in,
                              void* d_out, int out_size, void* d_ws,
                              size_t ws_size, hipStream_t stream) {
  const float* feats = (const float*)d_in[0];
  const float* rois  = (const float*)d_in[1];
  float* out         = (float*)d_out;

  const size_t need = (size_t)N_IMGS * IMG_ELEMS * sizeof(float);
  if (ws_size >= need) {
    float* nhwc = (float*)d_ws;
    dim3 tb(32, 8);
    dim3 tg(HW / 32, C / 32, N_IMGS);
    transpose_nchw_nhwc<<<tg, tb, 0, stream>>>(feats, nhwc);
    roi_align_kernel<true><<<dim3(R * 2), dim3(512), 0, stream>>>(nhwc, rois,
                                                                  out);
  } else {
    // Safety fallback: direct NCHW gathers (uncoalesced but correct).
    roi_align_kernel<false><<<dim3(R * 2), dim3(512), 0, stream>>>(feats, rois,
                                                                   out);
  }
}

// Round 5
// 146.938 us; speedup vs baseline: 2.5824x; 2.5824x over previous
//
#include <hip/hip_runtime.h>

#define N_IMGS 8
#define C 256
#define H 128
#define W 128
#define R 1024
#define HOUT 14
#define WOUT 14
#define NPOS 196          // HOUT*WOUT
#define HW (H * W)        // 16384
#define IMG_ELEMS (C * HW)
#define CTILE 32          // channels per block
#define NCT (C / CTILE)   // 8 channel tiles per roi
#define TILE_ELEMS (CTILE * NPOS)  // 6272 floats, contiguous in output

// ---------------------------------------------------------------------------
// Kernel 1: NCHW -> NHWC transpose (per image: (C, HW) -> (HW, C)).
// 32x32 LDS tile, +1 pad. Measured at HBM roofline -- unchanged.
// ---------------------------------------------------------------------------
__global__ __launch_bounds__(256) void transpose_nchw_nhwc(
    const float* __restrict__ in, float* __restrict__ out) {
  __shared__ float tile[32][33];
  const int n   = blockIdx.z;
  const int hw0 = blockIdx.x * 32;
  const int c0  = blockIdx.y * 32;
  const float* inp = in + (size_t)n * IMG_ELEMS;
  float* outp      = out + (size_t)n * IMG_ELEMS;
  const int tx = threadIdx.x;  // 0..31
  const int ty = threadIdx.y;  // 0..7

#pragma unroll
  for (int i = 0; i < 4; ++i) {
    int cc = ty + i * 8;
    tile[cc][tx] = inp[(size_t)(c0 + cc) * HW + hw0 + tx];
  }
  __syncthreads();
#pragma unroll
  for (int i = 0; i < 4; ++i) {
    int hh = ty + i * 8;
    outp[(size_t)(hw0 + hh) * C + c0 + tx] = tile[tx][hh];
  }
}

// ---------------------------------------------------------------------------
// Kernel 2: RoI Align, LDS-staged output.
// Grid = R*8 blocks of 256 threads: r = bid>>3, channel tile c0 = (bid&7)*32.
// Thread: local channel lc = tid&31, position group g = tid>>5 (stride-8 over
// the 196 positions). Gathers: 32 consecutive channels per corner = 128B
// coalesced. Results staged in LDS laid out EXACTLY as the output slice
// (lc*196+p), then streamed out as float4: each wave stores 1024B contiguous
// -> every 64B line filled by one instruction -> no RMW write amplification
// (round 3: WRITE was 2.6x output because 16B lane-fragments at stride 784B
// evicted partial lines).
// ---------------------------------------------------------------------------
template <bool NHWC>
__global__ __launch_bounds__(256, 4) void roi_align_kernel(
    const float* __restrict__ feats, const float* __restrict__ rois,
    float* __restrict__ out) {
  __shared__ int4   s_off[NPOS];   // element offsets; NHWC: o*C, NCHW: o
  __shared__ float4 s_w[NPOS];
  __shared__ alignas(16) float s_res[TILE_ELEMS];  // [CTILE][NPOS] == out slice

  const int bid = blockIdx.x;
  const int r   = bid >> 3;
  const int c0  = (bid & 7) * CTILE;
  const int tid = threadIdx.x;
  const int lc  = tid & (CTILE - 1);
  const int g   = tid >> 5;  // 0..7

  const float bf = rois[r * 5 + 0];
  const float x1 = rois[r * 5 + 1];
  const float y1 = rois[r * 5 + 2];
  const float x2 = rois[r * 5 + 3];
  const float y2 = rois[r * 5 + 4];
  const int   n  = (int)bf;

  if (tid < NPOS) {
    const int ph = tid / WOUT;
    const int pw = tid - ph * WOUT;
    const float px_rel = (pw + 0.5f) / (float)WOUT;
    const float py_rel = (ph + 0.5f) / (float)HOUT;
    const float x_abs = px_rel * (x2 - x1) + x1;
    const float y_abs = py_rel * (y2 - y1) + y1;
    // rx = x_abs / W * 0.25 ; px = rx * W - 0.5  ==  x_abs * 0.25 - 0.5
    const float px = x_abs * 0.25f - 0.5f;
    const float py = y_abs * 0.25f - 0.5f;
    const float x0f = floorf(px);
    const float y0f = floorf(py);
    const float lx = px - x0f, ly = py - y0f;
    const float hx = 1.0f - lx, hy = 1.0f - ly;
    const int ix0 = (int)x0f;
    const int iy0 = (int)y0f;
    const int ix1 = ix0 + 1;
    const int iy1 = iy0 + 1;
    // Reference pads with zeros and clips into the pad -> OOB corners
    // contribute exactly 0. Reproduce by zeroing the weight.
    const bool vx0 = (ix0 >= 0) && (ix0 < W);
    const bool vx1 = (ix1 >= 0) && (ix1 < W);
    const bool vy0 = (iy0 >= 0) && (iy0 < H);
    const bool vy1 = (iy1 >= 0) && (iy1 < H);
    const int cx0 = min(max(ix0, 0), W - 1);
    const int cx1 = min(max(ix1, 0), W - 1);
    const int cy0 = min(max(iy0, 0), H - 1);
    const int cy1 = min(max(iy1, 0), H - 1);
    const int scale = NHWC ? C : 1;
    int4 o;
    o.x = (cy0 * W + cx0) * scale;
    o.y = (cy1 * W + cx0) * scale;
    o.z = (cy0 * W + cx1) * scale;
    o.w = (cy1 * W + cx1) * scale;
    float4 w4;
    w4.x = (vx0 && vy0) ? hx * hy : 0.0f;
    w4.y = (vx0 && vy1) ? hx * ly : 0.0f;
    w4.z = (vx1 && vy0) ? lx * hy : 0.0f;
    w4.w = (vx1 && vy1) ? lx * ly : 0.0f;
    s_off[tid] = o;
    s_w[tid]   = w4;
  }
  __syncthreads();

  const int c = c0 + lc;
  // NHWC: base pre-offset by channel, gather = base[o] with o pre-scaled by C.
  // NCHW fallback: base = channel plane.
  const float* base = NHWC ? (feats + (size_t)n * IMG_ELEMS + c)
                           : (feats + (size_t)n * IMG_ELEMS + (size_t)c * HW);
  float* s_row = s_res + lc * NPOS;

  // Positions g, g+8, g+16, ... (24 or 25 of them). Batches of 4 positions:
  // 16 gathers issued before any FMA.
  int p = g;
#pragma unroll 1
  for (; p + 24 < NPOS; p += 32) {
    float  va[4], vb[4], vc[4], vd[4];
    float4 wt[4];
#pragma unroll
    for (int k = 0; k < 4; ++k) {
      const int pp = p + 8 * k;
      const int4 o = s_off[pp];
      wt[k] = s_w[pp];
      va[k] = base[o.x];
      vb[k] = base[o.y];
      vc[k] = base[o.z];
      vd[k] = base[o.w];
    }
#pragma unroll
    for (int k = 0; k < 4; ++k) {
      s_row[p + 8 * k] = va[k] * wt[k].x + vb[k] * wt[k].y + vc[k] * wt[k].z +
                         vd[k] * wt[k].w;
    }
  }
#pragma unroll 1
  for (; p < NPOS; p += 8) {  // tail (at most 1 iteration)
    const int4   o = s_off[p];
    const float4 w = s_w[p];
    s_row[p] = base[o.x] * w.x + base[o.y] * w.y + base[o.z] * w.z +
               base[o.w] * w.w;
  }
  __syncthreads();

  // Stream the tile out: contiguous 25088B region, float4 per thread.
  // Each wave writes 1024B contiguous -> full 64B lines, no RMW.
  const float4* s4 = reinterpret_cast<const float4*>(s_res);
  float4* out4 = reinterpret_cast<float4*>(out + ((size_t)r * C + c0) * NPOS);
#pragma unroll 1
  for (int i = tid; i < TILE_ELEMS / 4; i += 256) {
    out4[i] = s4[i];
  }
}

extern "C" void kernel_launch(void* const* d_in, const int* in_sizes, int n_in,
                              void* d_out, int out_size, void* d_ws,
                              size_t ws_size, hipStream_t stream) {
  const float* feats = (const float*)d_in[0];
  const float* rois  = (const float*)d_in[1];
  float* out         = (float*)d_out;

  const size_t need = (size_t)N_IMGS * IMG_ELEMS * sizeof(float);
  if (ws_size >= need) {
    float* nhwc = (float*)d_ws;
    dim3 tb(32, 8);
    dim3 tg(HW / 32, C / 32, N_IMGS);
    transpose_nchw_nhwc<<<tg, tb, 0, stream>>>(feats, nhwc);
    roi_align_kernel<true><<<dim3(R * NCT), dim3(256), 0, stream>>>(nhwc, rois,
                                                                    out);
  } else {
    // Safety fallback: direct NCHW gathers (uncoalesced but correct).
    roi_align_kernel<false><<<dim3(R * NCT), dim3(256), 0, stream>>>(
        feats, rois, out);
  }
}

// Round 7
// 117.590 us; speedup vs baseline: 3.2269x; 1.2496x over previous
//
#include <hip/hip_runtime.h>

#define N_IMGS 8
#define C 256
#define H 128
#define W 128
#define R 1024
#define HOUT 14
#define WOUT 14
#define NPOS 196          // HOUT*WOUT
#define HW (H * W)        // 16384
#define IMG_ELEMS (C * HW)
#define CTILE 32          // channels per block
#define NCT (C / CTILE)   // 8 channel tiles per roi
#define TILE_ELEMS (CTILE * NPOS)  // 6272 floats, contiguous in output

typedef float f4_t __attribute__((ext_vector_type(4)));  // native vec for NT store

// ---------------------------------------------------------------------------
// Kernel 1: NCHW -> NHWC transpose (per image: (C, HW) -> (HW, C)).
// 32x32 LDS tile, +1 pad. ~BW-bound, unchanged.
// ---------------------------------------------------------------------------
__global__ __launch_bounds__(256) void transpose_nchw_nhwc(
    const float* __restrict__ in, float* __restrict__ out) {
  __shared__ float tile[32][33];
  const int n   = blockIdx.z;
  const int hw0 = blockIdx.x * 32;
  const int c0  = blockIdx.y * 32;
  const float* inp = in + (size_t)n * IMG_ELEMS;
  float* outp      = out + (size_t)n * IMG_ELEMS;
  const int tx = threadIdx.x;  // 0..31
  const int ty = threadIdx.y;  // 0..7

#pragma unroll
  for (int i = 0; i < 4; ++i) {
    int cc = ty + i * 8;
    tile[cc][tx] = inp[(size_t)(c0 + cc) * HW + hw0 + tx];
  }
  __syncthreads();
#pragma unroll
  for (int i = 0; i < 4; ++i) {
    int hh = ty + i * 8;
    outp[(size_t)(hw0 + hh) * C + c0 + tx] = tile[tx][hh];
  }
}

// ---------------------------------------------------------------------------
// Geometry precompute shared by both roi kernels: offsets (pre-scaled) and
// bilinear weights for all 196 positions of roi r into LDS.
// ---------------------------------------------------------------------------
template <int SCALE>
__device__ __forceinline__ void setup_roi(const float* __restrict__ rois,
                                          int r, int tid, int4* s_off,
                                          float4* s_w, int* s_n) {
  const float bf = rois[r * 5 + 0];
  const float x1 = rois[r * 5 + 1];
  const float y1 = rois[r * 5 + 2];
  const float x2 = rois[r * 5 + 3];
  const float y2 = rois[r * 5 + 4];
  if (tid == 0) *s_n = (int)bf;

  if (tid < NPOS) {
    const int ph = tid / WOUT;
    const int pw = tid - ph * WOUT;
    const float px_rel = (pw + 0.5f) / (float)WOUT;
    const float py_rel = (ph + 0.5f) / (float)HOUT;
    const float x_abs = px_rel * (x2 - x1) + x1;
    const float y_abs = py_rel * (y2 - y1) + y1;
    // rx = x_abs / W * 0.25 ; px = rx * W - 0.5  ==  x_abs * 0.25 - 0.5
    const float px = x_abs * 0.25f - 0.5f;
    const float py = y_abs * 0.25f - 0.5f;
    const float x0f = floorf(px);
    const float y0f = floorf(py);
    const float lx = px - x0f, ly = py - y0f;
    const float hx = 1.0f - lx, hy = 1.0f - ly;
    const int ix0 = (int)x0f;
    const int iy0 = (int)y0f;
    const int ix1 = ix0 + 1;
    const int iy1 = iy0 + 1;
    // Reference pads with zeros and clips into the pad -> OOB corners
    // contribute exactly 0. Reproduce by zeroing the weight.
    const bool vx0 = (ix0 >= 0) && (ix0 < W);
    const bool vx1 = (ix1 >= 0) && (ix1 < W);
    const bool vy0 = (iy0 >= 0) && (iy0 < H);
    const bool vy1 = (iy1 >= 0) && (iy1 < H);
    const int cx0 = min(max(ix0, 0), W - 1);
    const int cx1 = min(max(ix1, 0), W - 1);
    const int cy0 = min(max(iy0, 0), H - 1);
    const int cy1 = min(max(iy1, 0), H - 1);
    int4 o;
    o.x = (cy0 * W + cx0) * SCALE;
    o.y = (cy1 * W + cx0) * SCALE;
    o.z = (cy0 * W + cx1) * SCALE;
    o.w = (cy1 * W + cx1) * SCALE;
    float4 w4;
    w4.x = (vx0 && vy0) ? hx * hy : 0.0f;
    w4.y = (vx0 && vy1) ? hx * ly : 0.0f;
    w4.z = (vx1 && vy0) ? lx * hy : 0.0f;
    w4.w = (vx1 && vy1) ? lx * ly : 0.0f;
    s_off[tid] = o;
    s_w[tid]   = w4;
  }
}

// ---------------------------------------------------------------------------
// Kernel 2: RoI Align, NHWC input, float4 channel-quad gathers.
// Grid = R*8 blocks of 256 threads: r = bid>>3, channel tile c0 = (bid&7)*32.
// Thread: channel-quad lc4 = tid&7 (4 consecutive channels), position group
// g = tid>>3 (positions g, g+32, ..., 196 = 32*6+4). Each corner gather is a
// float4 over 4 channels: 8 quads x 16B = 128B coalesced per corner, 4x fewer
// vector-mem instructions than scalar. Batch of 4 positions = 16 outstanding
// 16B loads/thread. Results staged in LDS in exact output layout, then
// streamed out with nontemporal float4 stores (full 64B lines, no RMW, no L2
// pollution).
// ---------------------------------------------------------------------------
__global__ __launch_bounds__(256, 4) void roi_align_nhwc(
    const float* __restrict__ feats, const float* __restrict__ rois,
    float* __restrict__ out) {
  __shared__ int4   s_off[NPOS];   // element offsets, pre-scaled by C
  __shared__ float4 s_w[NPOS];
  __shared__ alignas(16) float s_res[TILE_ELEMS];  // [CTILE][NPOS] = out slice
  __shared__ int s_n;

  const int bid = blockIdx.x;
  const int r   = bid >> 3;
  const int c0  = (bid & 7) * CTILE;
  const int tid = threadIdx.x;
  const int lc4 = tid & 7;   // channel quad within tile
  const int g   = tid >> 3;  // 0..31 position group

  setup_roi<C>(rois, r, tid, s_off, s_w, &s_n);
  __syncthreads();

  const int n = s_n;
  const float* base = feats + (size_t)n * IMG_ELEMS + c0 + lc4 * 4;
  const int chb = lc4 * 4;

  // Batch A: positions g + 32*{0,1,2,3} (all valid: max 127 < 196).
  {
    float4 A[4], B[4], Cc[4], D[4], Wt[4];
#pragma unroll
    for (int k = 0; k < 4; ++k) {
      const int p = g + 32 * k;
      const int4 o = s_off[p];
      Wt[k] = s_w[p];
      A[k]  = *reinterpret_cast<const float4*>(base + o.x);
      B[k]  = *reinterpret_cast<const float4*>(base + o.y);
      Cc[k] = *reinterpret_cast<const float4*>(base + o.z);
      D[k]  = *reinterpret_cast<const float4*>(base + o.w);
    }
#pragma unroll
    for (int k = 0; k < 4; ++k) {
      const int p = g + 32 * k;
      s_res[(chb + 0) * NPOS + p] =
          A[k].x * Wt[k].x + B[k].x * Wt[k].y + Cc[k].x * Wt[k].z + D[k].x * Wt[k].w;
      s_res[(chb + 1) * NPOS + p] =
          A[k].y * Wt[k].x + B[k].y * Wt[k].y + Cc[k].y * Wt[k].z + D[k].y * Wt[k].w;
      s_res[(chb + 2) * NPOS + p] =
          A[k].z * Wt[k].x + B[k].z * Wt[k].y + Cc[k].z * Wt[k].z + D[k].z * Wt[k].w;
      s_res[(chb + 3) * NPOS + p] =
          A[k].w * Wt[k].x + B[k].w * Wt[k].y + Cc[k].w * Wt[k].z + D[k].w * Wt[k].w;
    }
  }
  // Batch B: positions g + 32*{4,5} (max 191 < 196, all valid).
  {
    float4 A[2], B[2], Cc[2], D[2], Wt[2];
#pragma unroll
    for (int k = 0; k < 2; ++k) {
      const int p = g + 32 * (4 + k);
      const int4 o = s_off[p];
      Wt[k] = s_w[p];
      A[k]  = *reinterpret_cast<const float4*>(base + o.x);
      B[k]  = *reinterpret_cast<const float4*>(base + o.y);
      Cc[k] = *reinterpret_cast<const float4*>(base + o.z);
      D[k]  = *reinterpret_cast<const float4*>(base + o.w);
    }
#pragma unroll
    for (int k = 0; k < 2; ++k) {
      const int p = g + 32 * (4 + k);
      s_res[(chb + 0) * NPOS + p] =
          A[k].x * Wt[k].x + B[k].x * Wt[k].y + Cc[k].x * Wt[k].z + D[k].x * Wt[k].w;
      s_res[(chb + 1) * NPOS + p] =
          A[k].y * Wt[k].x + B[k].y * Wt[k].y + Cc[k].y * Wt[k].z + D[k].y * Wt[k].w;
      s_res[(chb + 2) * NPOS + p] =
          A[k].z * Wt[k].x + B[k].z * Wt[k].y + Cc[k].z * Wt[k].z + D[k].z * Wt[k].w;
      s_res[(chb + 3) * NPOS + p] =
          A[k].w * Wt[k].x + B[k].w * Wt[k].y + Cc[k].w * Wt[k].z + D[k].w * Wt[k].w;
    }
  }
  // Tail: position 192 + g, only groups g < 4.
  if (g < 4) {
    const int p = 192 + g;
    const int4   o = s_off[p];
    const float4 w = s_w[p];
    const float4 A  = *reinterpret_cast<const float4*>(base + o.x);
    const float4 B  = *reinterpret_cast<const float4*>(base + o.y);
    const float4 Cc = *reinterpret_cast<const float4*>(base + o.z);
    const float4 D  = *reinterpret_cast<const float4*>(base + o.w);
    s_res[(chb + 0) * NPOS + p] = A.x * w.x + B.x * w.y + Cc.x * w.z + D.x * w.w;
    s_res[(chb + 1) * NPOS + p] = A.y * w.x + B.y * w.y + Cc.y * w.z + D.y * w.w;
    s_res[(chb + 2) * NPOS + p] = A.z * w.x + B.z * w.y + Cc.z * w.z + D.z * w.w;
    s_res[(chb + 3) * NPOS + p] = A.w * w.x + B.w * w.y + Cc.w * w.z + D.w * w.w;
  }
  __syncthreads();

  // Stream the tile out: contiguous 25088B, nontemporal 16B stores
  // (native ext_vector type -- HIP's float4 class is rejected by the builtin).
  const f4_t* s4 = reinterpret_cast<const f4_t*>(s_res);
  f4_t* out4 = reinterpret_cast<f4_t*>(out + ((size_t)r * C + c0) * NPOS);
#pragma unroll 1
  for (int i = tid; i < TILE_ELEMS / 4; i += 256) {
    __builtin_nontemporal_store(s4[i], &out4[i]);
  }
}

// ---------------------------------------------------------------------------
// Fallback (ws too small): scalar gathers straight from NCHW. Correct, slow.
// ---------------------------------------------------------------------------
__global__ __launch_bounds__(256, 4) void roi_align_nchw(
    const float* __restrict__ feats, const float* __restrict__ rois,
    float* __restrict__ out) {
  __shared__ int4   s_off[NPOS];
  __shared__ float4 s_w[NPOS];
  __shared__ alignas(16) float s_res[TILE_ELEMS];
  __shared__ int s_n;

  const int bid = blockIdx.x;
  const int r   = bid >> 3;
  const int c0  = (bid & 7) * CTILE;
  const int tid = threadIdx.x;
  const int lc  = tid & (CTILE - 1);
  const int g   = tid >> 5;  // 0..7

  setup_roi<1>(rois, r, tid, s_off, s_w, &s_n);
  __syncthreads();

  const float* base = feats + (size_t)s_n * IMG_ELEMS + (size_t)(c0 + lc) * HW;
  float* s_row = s_res + lc * NPOS;
#pragma unroll 1
  for (int p = g; p < NPOS; p += 8) {
    const int4   o = s_off[p];
    const float4 w = s_w[p];
    s_row[p] = base[o.x] * w.x + base[o.y] * w.y + base[o.z] * w.z +
               base[o.w] * w.w;
  }
  __syncthreads();

  const float4* s4 = reinterpret_cast<const float4*>(s_res);
  float4* out4 = reinterpret_cast<float4*>(out + ((size_t)r * C + c0) * NPOS);
#pragma unroll 1
  for (int i = tid; i < TILE_ELEMS / 4; i += 256) {
    out4[i] = s4[i];
  }
}

extern "C" void kernel_launch(void* const* d_in, const int* in_sizes, int n_in,
                              void* d_out, int out_size, void* d_ws,
                              size_t ws_size, hipStream_t stream) {
  const float* feats = (const float*)d_in[0];
  const float* rois  = (const float*)d_in[1];
  float* out         = (float*)d_out;

  const size_t need = (size_t)N_IMGS * IMG_ELEMS * sizeof(float);
  if (ws_size >= need) {
    float* nhwc = (float*)d_ws;
    dim3 tb(32, 8);
    dim3 tg(HW / 32, C / 32, N_IMGS);
    transpose_nchw_nhwc<<<tg, tb, 0, stream>>>(feats, nhwc);
    roi_align_nhwc<<<dim3(R * NCT), dim3(256), 0, stream>>>(nhwc, rois, out);
  } else {
    roi_align_nchw<<<dim3(R * NCT), dim3(256), 0, stream>>>(feats, rois, out);
  }
}

// Round 8
// 106.129 us; speedup vs baseline: 3.5754x; 1.1080x over previous
//
#include <hip/hip_runtime.h>
#include <stdint.h>

#define N_IMGS 8
#define C 256
#define H 128
#define W 128
#define R 1024
#define HOUT 14
#define WOUT 14
#define NPOS 196          // HOUT*WOUT
#define HW (H * W)        // 16384
#define IMG_ELEMS (C * HW)
#define CTILE 32          // channels per block (roi kernel)
#define NCT (C / CTILE)   // 8 channel tiles per roi
#define TILE_ELEMS (CTILE * NPOS)  // 6272 floats, contiguous in output
#define CU (C / 2)        // uints per NHWC row (bf16-pair packed) = 128

typedef float f4_t __attribute__((ext_vector_type(4)));  // native vec for NT store

__device__ __forceinline__ unsigned short f2bf(float f) {  // RTNE
  uint32_t u = __float_as_uint(f);
  uint32_t r = u + 0x7FFFu + ((u >> 16) & 1u);
  return (unsigned short)(r >> 16);
}

// ---------------------------------------------------------------------------
// Kernel 1: NCHW -> NHWC transpose with bf16 pack.
// Per block: 64 channels x 32 hw. LDS float tile[64][33]. Loads coalesced
// (128B/instr); stores pack 2 channels into one uint -> 128B/instr. Tile
// reads in write phase are 2-way bank aliased (free). Output row (hw, c)
// is C/2 uints; uint k = channels {2k (lo), 2k+1 (hi)}.
// ---------------------------------------------------------------------------
__global__ __launch_bounds__(256) void transpose_nchw_nhwc_bf16(
    const float* __restrict__ in, uint32_t* __restrict__ out) {
  __shared__ float tile[64][33];
  const int n   = blockIdx.z;
  const int hw0 = blockIdx.x * 32;
  const int c0  = blockIdx.y * 64;
  const float* inp = in + (size_t)n * IMG_ELEMS;
  uint32_t* outp   = out + (size_t)n * (size_t)HW * CU;
  const int tx = threadIdx.x;  // 0..31
  const int ty = threadIdx.y;  // 0..7

#pragma unroll
  for (int i = 0; i < 8; ++i) {
    int cc = ty + i * 8;  // 0..63
    tile[cc][tx] = inp[(size_t)(c0 + cc) * HW + hw0 + tx];
  }
  __syncthreads();
#pragma unroll
  for (int i = 0; i < 4; ++i) {
    int hh = ty + i * 8;  // 0..31
    const uint32_t lo = f2bf(tile[2 * tx + 0][hh]);
    const uint32_t hi = f2bf(tile[2 * tx + 1][hh]);
    outp[(size_t)(hw0 + hh) * CU + (c0 >> 1) + tx] = lo | (hi << 16);
  }
}

// ---------------------------------------------------------------------------
// Geometry precompute: offsets (pre-scaled by SCALE) and bilinear weights
// for all 196 positions of roi r into LDS.
// ---------------------------------------------------------------------------
template <int SCALE>
__device__ __forceinline__ void setup_roi(const float* __restrict__ rois,
                                          int r, int tid, int4* s_off,
                                          float4* s_w, int* s_n) {
  const float bf = rois[r * 5 + 0];
  const float x1 = rois[r * 5 + 1];
  const float y1 = rois[r * 5 + 2];
  const float x2 = rois[r * 5 + 3];
  const float y2 = rois[r * 5 + 4];
  if (tid == 0) *s_n = (int)bf;

  if (tid < NPOS) {
    const int ph = tid / WOUT;
    const int pw = tid - ph * WOUT;
    const float px_rel = (pw + 0.5f) / (float)WOUT;
    const float py_rel = (ph + 0.5f) / (float)HOUT;
    const float x_abs = px_rel * (x2 - x1) + x1;
    const float y_abs = py_rel * (y2 - y1) + y1;
    // rx = x_abs / W * 0.25 ; px = rx * W - 0.5  ==  x_abs * 0.25 - 0.5
    const float px = x_abs * 0.25f - 0.5f;
    const float py = y_abs * 0.25f - 0.5f;
    const float x0f = floorf(px);
    const float y0f = floorf(py);
    const float lx = px - x0f, ly = py - y0f;
    const float hx = 1.0f - lx, hy = 1.0f - ly;
    const int ix0 = (int)x0f;
    const int iy0 = (int)y0f;
    const int ix1 = ix0 + 1;
    const int iy1 = iy0 + 1;
    // Reference pads with zeros and clips into the pad -> OOB corners
    // contribute exactly 0. Reproduce by zeroing the weight.
    const bool vx0 = (ix0 >= 0) && (ix0 < W);
    const bool vx1 = (ix1 >= 0) && (ix1 < W);
    const bool vy0 = (iy0 >= 0) && (iy0 < H);
    const bool vy1 = (iy1 >= 0) && (iy1 < H);
    const int cx0 = min(max(ix0, 0), W - 1);
    const int cx1 = min(max(ix1, 0), W - 1);
    const int cy0 = min(max(iy0, 0), H - 1);
    const int cy1 = min(max(iy1, 0), H - 1);
    int4 o;
    o.x = (cy0 * W + cx0) * SCALE;
    o.y = (cy1 * W + cx0) * SCALE;
    o.z = (cy0 * W + cx1) * SCALE;
    o.w = (cy1 * W + cx1) * SCALE;
    float4 w4;
    w4.x = (vx0 && vy0) ? hx * hy : 0.0f;
    w4.y = (vx0 && vy1) ? hx * ly : 0.0f;
    w4.z = (vx1 && vy0) ? lx * hy : 0.0f;
    w4.w = (vx1 && vy1) ? lx * ly : 0.0f;
    s_off[tid] = o;
    s_w[tid]   = w4;
  }
}

__device__ __forceinline__ void unpack8(uint4 q, float* f) {
  f[0] = __uint_as_float(q.x << 16);
  f[1] = __uint_as_float(q.x & 0xFFFF0000u);
  f[2] = __uint_as_float(q.y << 16);
  f[3] = __uint_as_float(q.y & 0xFFFF0000u);
  f[4] = __uint_as_float(q.z << 16);
  f[5] = __uint_as_float(q.z & 0xFFFF0000u);
  f[6] = __uint_as_float(q.w << 16);
  f[7] = __uint_as_float(q.w & 0xFFFF0000u);
}

__device__ __forceinline__ void acc8(float* s_base, int p, uint4 a, uint4 b,
                                     uint4 c, uint4 d, float4 w) {
  float fa[8], fb[8], fc[8], fd[8];
  unpack8(a, fa);
  unpack8(b, fb);
  unpack8(c, fc);
  unpack8(d, fd);
#pragma unroll
  for (int j = 0; j < 8; ++j) {
    s_base[j * NPOS + p] =
        fa[j] * w.x + fb[j] * w.y + fc[j] * w.z + fd[j] * w.w;
  }
}

// ---------------------------------------------------------------------------
// Kernel 2: RoI Align, bf16 NHWC input, uint4 = 8-channel gathers.
// Grid = R*8 blocks of 256 threads: r = bid>>3, channel tile c0 = (bid&7)*32.
// Thread: channel octet lc8 = tid&3 (8 consecutive channels), position group
// g = tid>>2 (positions g, g+64, g+128; 196 = 64*3+4, tail for g<4).
// Each corner gather = uint4 (8 bf16 channels): 4 octets x 16B = 64B full
// lines; 12 loads in flight per thread before any FMA. Unpack = 2 bit-ops
// per channel pair. Results staged in LDS in exact output layout, streamed
// out with nontemporal 16B stores (full 64B lines, no RMW).
// ---------------------------------------------------------------------------
__global__ __launch_bounds__(256, 4) void roi_align_nhwc_bf16(
    const uint32_t* __restrict__ feats, const float* __restrict__ rois,
    float* __restrict__ out) {
  __shared__ int4   s_off[NPOS];   // uint-offsets, pre-scaled by CU
  __shared__ float4 s_w[NPOS];
  __shared__ alignas(16) float s_res[TILE_ELEMS];  // [CTILE][NPOS] = out slice
  __shared__ int s_n;

  const int bid = blockIdx.x;
  const int r   = bid >> 3;
  const int c0  = (bid & 7) * CTILE;
  const int tid = threadIdx.x;
  const int lc8 = tid & 3;   // channel octet within tile
  const int g   = tid >> 2;  // 0..63 position group

  setup_roi<CU>(rois, r, tid, s_off, s_w, &s_n);
  __syncthreads();

  const uint32_t* base =
      feats + (size_t)s_n * (size_t)HW * CU + (c0 >> 1) + lc8 * 4;
  float* s_base = s_res + (lc8 * 8) * NPOS;

  // Main: positions g + 64*{0,1,2} (max 190 < 196, all valid).
  {
    uint4 A[3], B[3], Cc[3], D[3];
    float4 Wt[3];
#pragma unroll
    for (int k = 0; k < 3; ++k) {
      const int p = g + 64 * k;
      const int4 o = s_off[p];
      Wt[k] = s_w[p];
      A[k]  = *reinterpret_cast<const uint4*>(base + o.x);
      B[k]  = *reinterpret_cast<const uint4*>(base + o.y);
      Cc[k] = *reinterpret_cast<const uint4*>(base + o.z);
      D[k]  = *reinterpret_cast<const uint4*>(base + o.w);
    }
#pragma unroll
    for (int k = 0; k < 3; ++k) {
      acc8(s_base, g + 64 * k, A[k], B[k], Cc[k], D[k], Wt[k]);
    }
  }
  // Tail: position 192 + g, only groups g < 4.
  if (g < 4) {
    const int p = 192 + g;
    const int4   o = s_off[p];
    const float4 w = s_w[p];
    const uint4 A  = *reinterpret_cast<const uint4*>(base + o.x);
    const uint4 B  = *reinterpret_cast<const uint4*>(base + o.y);
    const uint4 Cc = *reinterpret_cast<const uint4*>(base + o.z);
    const uint4 D  = *reinterpret_cast<const uint4*>(base + o.w);
    acc8(s_base, p, A, B, Cc, D, w);
  }
  __syncthreads();

  // Stream the tile out: contiguous 25088B, nontemporal 16B stores.
  const f4_t* s4 = reinterpret_cast<const f4_t*>(s_res);
  f4_t* out4 = reinterpret_cast<f4_t*>(out + ((size_t)r * C + c0) * NPOS);
#pragma unroll 1
  for (int i = tid; i < TILE_ELEMS / 4; i += 256) {
    __builtin_nontemporal_store(s4[i], &out4[i]);
  }
}

// ---------------------------------------------------------------------------
// Fallback (ws too small): scalar gathers straight from NCHW. Correct, slow.
// ---------------------------------------------------------------------------
__global__ __launch_bounds__(256, 4) void roi_align_nchw(
    const float* __restrict__ feats, const float* __restrict__ rois,
    float* __restrict__ out) {
  __shared__ int4   s_off[NPOS];
  __shared__ float4 s_w[NPOS];
  __shared__ alignas(16) float s_res[TILE_ELEMS];
  __shared__ int s_n;

  const int bid = blockIdx.x;
  const int r   = bid >> 3;
  const int c0  = (bid & 7) * CTILE;
  const int tid = threadIdx.x;
  const int lc  = tid & (CTILE - 1);
  const int g   = tid >> 5;  // 0..7

  setup_roi<1>(rois, r, tid, s_off, s_w, &s_n);
  __syncthreads();

  const float* base = feats + (size_t)s_n * IMG_ELEMS + (size_t)(c0 + lc) * HW;
  float* s_row = s_res + lc * NPOS;
#pragma unroll 1
  for (int p = g; p < NPOS; p += 8) {
    const int4   o = s_off[p];
    const float4 w = s_w[p];
    s_row[p] = base[o.x] * w.x + base[o.y] * w.y + base[o.z] * w.z +
               base[o.w] * w.w;
  }
  __syncthreads();

  const float4* s4 = reinterpret_cast<const float4*>(s_res);
  float4* out4 = reinterpret_cast<float4*>(out + ((size_t)r * C + c0) * NPOS);
#pragma unroll 1
  for (int i = tid; i < TILE_ELEMS / 4; i += 256) {
    out4[i] = s4[i];
  }
}

extern "C" void kernel_launch(void* const* d_in, const int* in_sizes, int n_in,
                              void* d_out, int out_size, void* d_ws,
                              size_t ws_size, hipStream_t stream) {
  const float* feats = (const float*)d_in[0];
  const float* rois  = (const float*)d_in[1];
  float* out         = (float*)d_out;

  const size_t need = (size_t)N_IMGS * IMG_ELEMS * sizeof(unsigned short);
  if (ws_size >= need) {
    uint32_t* nhwc16 = (uint32_t*)d_ws;
    dim3 tb(32, 8);
    dim3 tg(HW / 32, C / 64, N_IMGS);
    transpose_nchw_nhwc_bf16<<<tg, tb, 0, stream>>>(feats, nhwc16);
    roi_align_nhwc_bf16<<<dim3(R * NCT), dim3(256), 0, stream>>>(nhwc16, rois,
                                                                 out);
  } else {
    roi_align_nchw<<<dim3(R * NCT), dim3(256), 0, stream>>>(feats, rois, out);
  }
}

// Round 9
// 105.568 us; speedup vs baseline: 3.5944x; 1.0053x over previous
//
#include <hip/hip_runtime.h>
#include <stdint.h>

#define N_IMGS 8
#define C 256
#define H 128
#define W 128
#define R 1024
#define HOUT 14
#define WOUT 14
#define NPOS 196          // HOUT*WOUT
#define HW (H * W)        // 16384
#define IMG_ELEMS (C * HW)
#define CTILE 32          // channels per block (roi kernel)
#define NCT (C / CTILE)   // 8 channel tiles per roi
#define TILE_ELEMS (CTILE * NPOS)  // 6272 floats, contiguous in output
#define CU_ (C / 2)       // uints per NHWC row (bf16-pair packed) = 128

typedef float f4_t __attribute__((ext_vector_type(4)));  // native vec for NT store

__device__ __forceinline__ unsigned short f2bf(float f) {  // RTNE
  uint32_t u = __float_as_uint(f);
  uint32_t r = u + 0x7FFFu + ((u >> 16) & 1u);
  return (unsigned short)(r >> 16);
}

// ---------------------------------------------------------------------------
// Kernel 1: NCHW -> NHWC transpose with bf16 pack. Per block: 64ch x 32hw.
// Loads coalesced 128B/instr; stores pack 2 channels/uint -> 128B/instr.
// ---------------------------------------------------------------------------
__global__ __launch_bounds__(256) void transpose_nchw_nhwc_bf16(
    const float* __restrict__ in, uint32_t* __restrict__ out) {
  __shared__ float tile[64][33];
  const int n   = blockIdx.z;
  const int hw0 = blockIdx.x * 32;
  const int c0  = blockIdx.y * 64;
  const float* inp = in + (size_t)n * IMG_ELEMS;
  uint32_t* outp   = out + (size_t)n * (size_t)HW * CU_;
  const int tx = threadIdx.x;  // 0..31
  const int ty = threadIdx.y;  // 0..7

#pragma unroll
  for (int i = 0; i < 8; ++i) {
    int cc = ty + i * 8;  // 0..63
    tile[cc][tx] = inp[(size_t)(c0 + cc) * HW + hw0 + tx];
  }
  __syncthreads();
#pragma unroll
  for (int i = 0; i < 4; ++i) {
    int hh = ty + i * 8;  // 0..31
    const uint32_t lo = f2bf(tile[2 * tx + 0][hh]);
    const uint32_t hi = f2bf(tile[2 * tx + 1][hh]);
    outp[(size_t)(hw0 + hh) * CU_ + (c0 >> 1) + tx] = lo | (hi << 16);
  }
}

// ---------------------------------------------------------------------------
// Geometry precompute: offsets (pre-scaled by SCALE) and bilinear weights
// for all 196 positions of roi r into LDS.
// ---------------------------------------------------------------------------
template <int SCALE>
__device__ __forceinline__ void setup_roi(const float* __restrict__ rois,
                                          int r, int tid, int4* s_off,
                                          float4* s_w, int* s_n) {
  const float bf = rois[r * 5 + 0];
  const float x1 = rois[r * 5 + 1];
  const float y1 = rois[r * 5 + 2];
  const float x2 = rois[r * 5 + 3];
  const float y2 = rois[r * 5 + 4];
  if (tid == 0) *s_n = (int)bf;

  if (tid < NPOS) {
    const int ph = tid / WOUT;
    const int pw = tid - ph * WOUT;
    const float px_rel = (pw + 0.5f) / (float)WOUT;
    const float py_rel = (ph + 0.5f) / (float)HOUT;
    const float x_abs = px_rel * (x2 - x1) + x1;
    const float y_abs = py_rel * (y2 - y1) + y1;
    // rx = x_abs / W * 0.25 ; px = rx * W - 0.5  ==  x_abs * 0.25 - 0.5
    const float px = x_abs * 0.25f - 0.5f;
    const float py = y_abs * 0.25f - 0.5f;
    const float x0f = floorf(px);
    const float y0f = floorf(py);
    const float lx = px - x0f, ly = py - y0f;
    const float hx = 1.0f - lx, hy = 1.0f - ly;
    const int ix0 = (int)x0f;
    const int iy0 = (int)y0f;
    const int ix1 = ix0 + 1;
    const int iy1 = iy0 + 1;
    // Reference pads with zeros and clips into the pad -> OOB corners
    // contribute exactly 0. Reproduce by zeroing the weight.
    const bool vx0 = (ix0 >= 0) && (ix0 < W);
    const bool vx1 = (ix1 >= 0) && (ix1 < W);
    const bool vy0 = (iy0 >= 0) && (iy0 < H);
    const bool vy1 = (iy1 >= 0) && (iy1 < H);
    const int cx0 = min(max(ix0, 0), W - 1);
    const int cx1 = min(max(ix1, 0), W - 1);
    const int cy0 = min(max(iy0, 0), H - 1);
    const int cy1 = min(max(iy1, 0), H - 1);
    int4 o;
    o.x = (cy0 * W + cx0) * SCALE;
    o.y = (cy1 * W + cx0) * SCALE;
    o.z = (cy0 * W + cx1) * SCALE;
    o.w = (cy1 * W + cx1) * SCALE;
    float4 w4;
    w4.x = (vx0 && vy0) ? hx * hy : 0.0f;
    w4.y = (vx0 && vy1) ? hx * ly : 0.0f;
    w4.z = (vx1 && vy0) ? lx * hy : 0.0f;
    w4.w = (vx1 && vy1) ? lx * ly : 0.0f;
    s_off[tid] = o;
    s_w[tid]   = w4;
  }
}

__device__ __forceinline__ void unpack8(uint4 q, float* f) {
  f[0] = __uint_as_float(q.x << 16);
  f[1] = __uint_as_float(q.x & 0xFFFF0000u);
  f[2] = __uint_as_float(q.y << 16);
  f[3] = __uint_as_float(q.y & 0xFFFF0000u);
  f[4] = __uint_as_float(q.z << 16);
  f[5] = __uint_as_float(q.z & 0xFFFF0000u);
  f[6] = __uint_as_float(q.w << 16);
  f[7] = __uint_as_float(q.w & 0xFFFF0000u);
}

__device__ __forceinline__ void acc8(float* s_base, int p, uint4 a, uint4 b,
                                     uint4 c, uint4 d, float4 w) {
  float fa[8], fb[8], fc[8], fd[8];
  unpack8(a, fa);
  unpack8(b, fb);
  unpack8(c, fc);
  unpack8(d, fd);
#pragma unroll
  for (int j = 0; j < 8; ++j) {
    s_base[j * NPOS + p] =
        fa[j] * w.x + fb[j] * w.y + fc[j] * w.z + fd[j] * w.w;
  }
}

// ---------------------------------------------------------------------------
// Kernel 2: RoI Align, bf16 NHWC input, uint4 = 8-channel gathers.
// 512 threads/block (was 256): r = bid>>3, c0 = (bid&7)*32.
// Thread: channel octet lc8 = tid&3, position group g = tid>>2 in 0..127;
// positions p0 = g, p1 = 128+g (g<68). 8 uint4 gathers in flight/thread.
// __launch_bounds__(512,6): 24 waves/CU (75% vs round-8's 62.5% LDS-capped
// 20) -- LDS 3x31.4KB = 94KB, VGPR budget 85 fits the 8-load batch.
// Results staged in LDS in exact output layout; nontemporal full-line
// writeout unchanged.
// ---------------------------------------------------------------------------
__global__ __launch_bounds__(512, 6) void roi_align_nhwc_bf16(
    const uint32_t* __restrict__ feats, const float* __restrict__ rois,
    float* __restrict__ out) {
  __shared__ int4   s_off[NPOS];   // uint-offsets, pre-scaled by CU_
  __shared__ float4 s_w[NPOS];
  __shared__ alignas(16) float s_res[TILE_ELEMS];  // [CTILE][NPOS] = out slice
  __shared__ int s_n;

  const int bid = blockIdx.x;
  const int r   = bid >> 3;
  const int c0  = (bid & 7) * CTILE;
  const int tid = threadIdx.x;
  const int lc8 = tid & 3;   // channel octet within tile
  const int g   = tid >> 2;  // 0..127 position group

  setup_roi<CU_>(rois, r, tid, s_off, s_w, &s_n);
  __syncthreads();

  const uint32_t* base =
      feats + (size_t)s_n * (size_t)HW * CU_ + (c0 >> 1) + lc8 * 4;
  float* s_base = s_res + (lc8 * 8) * NPOS;

  const bool has1 = g < (NPOS - 128);  // g < 68
  const int p1 = 128 + g;

  // Issue all gathers (up to 8 uint4) before any consumption.
  const int4   o0 = s_off[g];
  const float4 w0 = s_w[g];
  uint4 A0 = *reinterpret_cast<const uint4*>(base + o0.x);
  uint4 B0 = *reinterpret_cast<const uint4*>(base + o0.y);
  uint4 C0 = *reinterpret_cast<const uint4*>(base + o0.z);
  uint4 D0 = *reinterpret_cast<const uint4*>(base + o0.w);
  if (has1) {
    const int4   o1 = s_off[p1];
    const float4 w1 = s_w[p1];
    const uint4 A1 = *reinterpret_cast<const uint4*>(base + o1.x);
    const uint4 B1 = *reinterpret_cast<const uint4*>(base + o1.y);
    const uint4 C1 = *reinterpret_cast<const uint4*>(base + o1.z);
    const uint4 D1 = *reinterpret_cast<const uint4*>(base + o1.w);
    acc8(s_base, g, A0, B0, C0, D0, w0);
    acc8(s_base, p1, A1, B1, C1, D1, w1);
  } else {
    acc8(s_base, g, A0, B0, C0, D0, w0);
  }
  __syncthreads();

  // Stream the tile out: contiguous 25088B, nontemporal 16B stores.
  const f4_t* s4 = reinterpret_cast<const f4_t*>(s_res);
  f4_t* out4 = reinterpret_cast<f4_t*>(out + ((size_t)r * C + c0) * NPOS);
#pragma unroll 1
  for (int i = tid; i < TILE_ELEMS / 4; i += 512) {
    __builtin_nontemporal_store(s4[i], &out4[i]);
  }
}

// ---------------------------------------------------------------------------
// Fallback (ws too small): scalar gathers straight from NCHW. Correct, slow.
// ---------------------------------------------------------------------------
__global__ __launch_bounds__(256, 4) void roi_align_nchw(
    const float* __restrict__ feats, const float* __restrict__ rois,
    float* __restrict__ out) {
  __shared__ int4   s_off[NPOS];
  __shared__ float4 s_w[NPOS];
  __shared__ alignas(16) float s_res[TILE_ELEMS];
  __shared__ int s_n;

  const int bid = blockIdx.x;
  const int r   = bid >> 3;
  const int c0  = (bid & 7) * CTILE;
  const int tid = threadIdx.x;
  const int lc  = tid & (CTILE - 1);
  const int g   = tid >> 5;  // 0..7

  setup_roi<1>(rois, r, tid, s_off, s_w, &s_n);
  __syncthreads();

  const float* base = feats + (size_t)s_n * IMG_ELEMS + (size_t)(c0 + lc) * HW;
  float* s_row = s_res + lc * NPOS;
#pragma unroll 1
  for (int p = g; p < NPOS; p += 8) {
    const int4   o = s_off[p];
    const float4 w = s_w[p];
    s_row[p] = base[o.x] * w.x + base[o.y] * w.y + base[o.z] * w.z +
               base[o.w] * w.w;
  }
  __syncthreads();

  const float4* s4 = reinterpret_cast<const float4*>(s_res);
  float4* out4 = reinterpret_cast<float4*>(out + ((size_t)r * C + c0) * NPOS);
#pragma unroll 1
  for (int i = tid; i < TILE_ELEMS / 4; i += 256) {
    out4[i] = s4[i];
  }
}

extern "C" void kernel_launch(void* const* d_in, const int* in_sizes, int n_in,
                              void* d_out, int out_size, void* d_ws,
                              size_t ws_size, hipStream_t stream) {
  const float* feats = (const float*)d_in[0];
  const float* rois  = (const float*)d_in[1];
  float* out         = (float*)d_out;

  const size_t need = (size_t)N_IMGS * IMG_ELEMS * sizeof(unsigned short);
  if (ws_size >= need) {
    uint32_t* nhwc16 = (uint32_t*)d_ws;
    dim3 tb(32, 8);
    dim3 tg(HW / 32, C / 64, N_IMGS);
    transpose_nchw_nhwc_bf16<<<tg, tb, 0, stream>>>(feats, nhwc16);
    roi_align_nhwc_bf16<<<dim3(R * NCT), dim3(512), 0, stream>>>(nhwc16, rois,
                                                                 out);
  } else {
    roi_align_nchw<<<dim3(R * NCT), dim3(256), 0, stream>>>(feats, rois, out);
  }
}

// Round 10
// 85.208 us; speedup vs baseline: 4.4532x; 1.2389x over previous
//
#include <hip/hip_runtime.h>
#include <stdint.h>

#define N_IMGS 8
#define C 256
#define H 128
#define W 128
#define R 1024
#define HOUT 14
#define WOUT 14
#define NPOS 196          // HOUT*WOUT
#define HW (H * W)        // 16384
#define IMG_ELEMS (C * HW)
#define CTILE 32          // channels per block (roi kernel)
#define NCT (C / CTILE)   // 8 channel tiles per roi
#define TILE_ELEMS (CTILE * NPOS)  // 6272 floats, contiguous in output
#define CU_ (C / 2)       // uints per NHWC row (bf16-pair packed) = 128

typedef float f4_t __attribute__((ext_vector_type(4)));  // native vec for NT store

__device__ __forceinline__ unsigned short f2bf(float f) {  // RTNE
  uint32_t u = __float_as_uint(f);
  uint32_t r = u + 0x7FFFu + ((u >> 16) & 1u);
  return (unsigned short)(r >> 16);
}

// ---------------------------------------------------------------------------
// Kernel 0: group roi indices by image (counting sort, 1 block, ~3us).
// perm[k] = roi index; rois of the same image are contiguous in perm.
// Output of the whole op is permutation-invariant (each roi owns its output
// slice), so nondeterministic within-bin order is harmless.
// ---------------------------------------------------------------------------
__global__ __launch_bounds__(256) void sort_rois_by_image(
    const float* __restrict__ rois, int* __restrict__ perm) {
  __shared__ int hist[N_IMGS];
  __shared__ int cursor[N_IMGS];
  const int tid = threadIdx.x;
  if (tid < N_IMGS) hist[tid] = 0;
  __syncthreads();
  for (int i = tid; i < R; i += 256) {
    atomicAdd(&hist[(int)rois[i * 5]], 1);
  }
  __syncthreads();
  if (tid == 0) {
    int acc = 0;
    for (int k = 0; k < N_IMGS; ++k) {
      cursor[k] = acc;
      acc += hist[k];
    }
  }
  __syncthreads();
  for (int i = tid; i < R; i += 256) {
    const int b = (int)rois[i * 5];
    const int pos = atomicAdd(&cursor[b], 1);
    perm[pos] = i;
  }
}

// ---------------------------------------------------------------------------
// Kernel 1: NCHW -> NHWC transpose with bf16 pack. Per block: 64ch x 32hw.
// Loads coalesced 128B/instr; stores pack 2 channels/uint -> 128B/instr.
// ~BW-bound (201MB round trip).
// ---------------------------------------------------------------------------
__global__ __launch_bounds__(256) void transpose_nchw_nhwc_bf16(
    const float* __restrict__ in, uint32_t* __restrict__ out) {
  __shared__ float tile[64][33];
  const int n   = blockIdx.z;
  const int hw0 = blockIdx.x * 32;
  const int c0  = blockIdx.y * 64;
  const float* inp = in + (size_t)n * IMG_ELEMS;
  uint32_t* outp   = out + (size_t)n * (size_t)HW * CU_;
  const int tx = threadIdx.x;  // 0..31
  const int ty = threadIdx.y;  // 0..7

#pragma unroll
  for (int i = 0; i < 8; ++i) {
    int cc = ty + i * 8;  // 0..63
    tile[cc][tx] = inp[(size_t)(c0 + cc) * HW + hw0 + tx];
  }
  __syncthreads();
#pragma unroll
  for (int i = 0; i < 4; ++i) {
    int hh = ty + i * 8;  // 0..31
    const uint32_t lo = f2bf(tile[2 * tx + 0][hh]);
    const uint32_t hi = f2bf(tile[2 * tx + 1][hh]);
    outp[(size_t)(hw0 + hh) * CU_ + (c0 >> 1) + tx] = lo | (hi << 16);
  }
}

// ---------------------------------------------------------------------------
// Geometry precompute: offsets (pre-scaled by SCALE) and bilinear weights
// for all 196 positions of roi r into LDS.
// ---------------------------------------------------------------------------
template <int SCALE>
__device__ __forceinline__ void setup_roi(const float* __restrict__ rois,
                                          int r, int tid, int4* s_off,
                                          float4* s_w, int* s_n) {
  const float bf = rois[r * 5 + 0];
  const float x1 = rois[r * 5 + 1];
  const float y1 = rois[r * 5 + 2];
  const float x2 = rois[r * 5 + 3];
  const float y2 = rois[r * 5 + 4];
  if (tid == 0) *s_n = (int)bf;

  if (tid < NPOS) {
    const int ph = tid / WOUT;
    const int pw = tid - ph * WOUT;
    const float px_rel = (pw + 0.5f) / (float)WOUT;
    const float py_rel = (ph + 0.5f) / (float)HOUT;
    const float x_abs = px_rel * (x2 - x1) + x1;
    const float y_abs = py_rel * (y2 - y1) + y1;
    // rx = x_abs / W * 0.25 ; px = rx * W - 0.5  ==  x_abs * 0.25 - 0.5
    const float px = x_abs * 0.25f - 0.5f;
    const float py = y_abs * 0.25f - 0.5f;
    const float x0f = floorf(px);
    const float y0f = floorf(py);
    const float lx = px - x0f, ly = py - y0f;
    const float hx = 1.0f - lx, hy = 1.0f - ly;
    const int ix0 = (int)x0f;
    const int iy0 = (int)y0f;
    const int ix1 = ix0 + 1;
    const int iy1 = iy0 + 1;
    // Reference pads with zeros and clips into the pad -> OOB corners
    // contribute exactly 0. Reproduce by zeroing the weight.
    const bool vx0 = (ix0 >= 0) && (ix0 < W);
    const bool vx1 = (ix1 >= 0) && (ix1 < W);
    const bool vy0 = (iy0 >= 0) && (iy0 < H);
    const bool vy1 = (iy1 >= 0) && (iy1 < H);
    const int cx0 = min(max(ix0, 0), W - 1);
    const int cx1 = min(max(ix1, 0), W - 1);
    const int cy0 = min(max(iy0, 0), H - 1);
    const int cy1 = min(max(iy1, 0), H - 1);
    int4 o;
    o.x = (cy0 * W + cx0) * SCALE;
    o.y = (cy1 * W + cx0) * SCALE;
    o.z = (cy0 * W + cx1) * SCALE;
    o.w = (cy1 * W + cx1) * SCALE;
    float4 w4;
    w4.x = (vx0 && vy0) ? hx * hy : 0.0f;
    w4.y = (vx0 && vy1) ? hx * ly : 0.0f;
    w4.z = (vx1 && vy0) ? lx * hy : 0.0f;
    w4.w = (vx1 && vy1) ? lx * ly : 0.0f;
    s_off[tid] = o;
    s_w[tid]   = w4;
  }
}

__device__ __forceinline__ void unpack8(uint4 q, float* f) {
  f[0] = __uint_as_float(q.x << 16);
  f[1] = __uint_as_float(q.x & 0xFFFF0000u);
  f[2] = __uint_as_float(q.y << 16);
  f[3] = __uint_as_float(q.y & 0xFFFF0000u);
  f[4] = __uint_as_float(q.z << 16);
  f[5] = __uint_as_float(q.z & 0xFFFF0000u);
  f[6] = __uint_as_float(q.w << 16);
  f[7] = __uint_as_float(q.w & 0xFFFF0000u);
}

__device__ __forceinline__ void acc8(float* s_base, int p, uint4 a, uint4 b,
                                     uint4 c, uint4 d, float4 w) {
  float fa[8], fb[8], fc[8], fd[8];
  unpack8(a, fa);
  unpack8(b, fb);
  unpack8(c, fc);
  unpack8(d, fd);
#pragma unroll
  for (int j = 0; j < 8; ++j) {
    s_base[j * NPOS + p] =
        fa[j] * w.x + fb[j] * w.y + fc[j] * w.z + fd[j] * w.w;
  }
}

// ---------------------------------------------------------------------------
// Kernel 2: RoI Align, bf16 NHWC input, uint4 = 8-channel gathers.
// 512 threads/block: roi = perm[bid>>3] (image-grouped), c0 = (bid&7)*32.
// Thread: channel octet lc8 = tid&3, position group g = tid>>2 in 0..127;
// positions p0 = g, p1 = 128+g (g<68). Image-grouped roi order + ctile==bid%8
// keeps each XCD's gather working set at ~1MB (one ctile-slice of one image)
// -> L2-resident instead of spilling to Infinity Cache.
// Results staged in LDS in exact output layout; nontemporal full-line
// writeout.
// ---------------------------------------------------------------------------
__global__ __launch_bounds__(512, 6) void roi_align_nhwc_bf16(
    const uint32_t* __restrict__ feats, const float* __restrict__ rois,
    const int* __restrict__ perm, float* __restrict__ out) {
  __shared__ int4   s_off[NPOS];   // uint-offsets, pre-scaled by CU_
  __shared__ float4 s_w[NPOS];
  __shared__ alignas(16) float s_res[TILE_ELEMS];  // [CTILE][NPOS] = out slice
  __shared__ int s_n;

  const int bid = blockIdx.x;
  const int r   = perm[bid >> 3];
  const int c0  = (bid & 7) * CTILE;
  const int tid = threadIdx.x;
  const int lc8 = tid & 3;   // channel octet within tile
  const int g   = tid >> 2;  // 0..127 position group

  setup_roi<CU_>(rois, r, tid, s_off, s_w, &s_n);
  __syncthreads();

  const uint32_t* base =
      feats + (size_t)s_n * (size_t)HW * CU_ + (c0 >> 1) + lc8 * 4;
  float* s_base = s_res + (lc8 * 8) * NPOS;

  const bool has1 = g < (NPOS - 128);  // g < 68
  const int p1 = 128 + g;

  // Issue all gathers (up to 8 uint4) before any consumption.
  const int4   o0 = s_off[g];
  const float4 w0 = s_w[g];
  uint4 A0 = *reinterpret_cast<const uint4*>(base + o0.x);
  uint4 B0 = *reinterpret_cast<const uint4*>(base + o0.y);
  uint4 C0 = *reinterpret_cast<const uint4*>(base + o0.z);
  uint4 D0 = *reinterpret_cast<const uint4*>(base + o0.w);
  if (has1) {
    const int4   o1 = s_off[p1];
    const float4 w1 = s_w[p1];
    const uint4 A1 = *reinterpret_cast<const uint4*>(base + o1.x);
    const uint4 B1 = *reinterpret_cast<const uint4*>(base + o1.y);
    const uint4 C1 = *reinterpret_cast<const uint4*>(base + o1.z);
    const uint4 D1 = *reinterpret_cast<const uint4*>(base + o1.w);
    acc8(s_base, g, A0, B0, C0, D0, w0);
    acc8(s_base, p1, A1, B1, C1, D1, w1);
  } else {
    acc8(s_base, g, A0, B0, C0, D0, w0);
  }
  __syncthreads();

  // Stream the tile out: contiguous 25088B, nontemporal 16B stores.
  const f4_t* s4 = reinterpret_cast<const f4_t*>(s_res);
  f4_t* out4 = reinterpret_cast<f4_t*>(out + ((size_t)r * C + c0) * NPOS);
#pragma unroll 1
  for (int i = tid; i < TILE_ELEMS / 4; i += 512) {
    __builtin_nontemporal_store(s4[i], &out4[i]);
  }
}

// ---------------------------------------------------------------------------
// Fallback (ws too small): scalar gathers straight from NCHW. Correct, slow.
// ---------------------------------------------------------------------------
__global__ __launch_bounds__(256, 4) void roi_align_nchw(
    const float* __restrict__ feats, const float* __restrict__ rois,
    float* __restrict__ out) {
  __shared__ int4   s_off[NPOS];
  __shared__ float4 s_w[NPOS];
  __shared__ alignas(16) float s_res[TILE_ELEMS];
  __shared__ int s_n;

  const int bid = blockIdx.x;
  const int r   = bid >> 3;
  const int c0  = (bid & 7) * CTILE;
  const int tid = threadIdx.x;
  const int lc  = tid & (CTILE - 1);
  const int g   = tid >> 5;  // 0..7

  setup_roi<1>(rois, r, tid, s_off, s_w, &s_n);
  __syncthreads();

  const float* base = feats + (size_t)s_n * IMG_ELEMS + (size_t)(c0 + lc) * HW;
  float* s_row = s_res + lc * NPOS;
#pragma unroll 1
  for (int p = g; p < NPOS; p += 8) {
    const int4   o = s_off[p];
    const float4 w = s_w[p];
    s_row[p] = base[o.x] * w.x + base[o.y] * w.y + base[o.z] * w.z +
               base[o.w] * w.w;
  }
  __syncthreads();

  const float4* s4 = reinterpret_cast<const float4*>(s_res);
  float4* out4 = reinterpret_cast<float4*>(out + ((size_t)r * C + c0) * NPOS);
#pragma unroll 1
  for (int i = tid; i < TILE_ELEMS / 4; i += 256) {
    out4[i] = s4[i];
  }
}

extern "C" void kernel_launch(void* const* d_in, const int* in_sizes, int n_in,
                              void* d_out, int out_size, void* d_ws,
                              size_t ws_size, hipStream_t stream) {
  const float* feats = (const float*)d_in[0];
  const float* rois  = (const float*)d_in[1];
  float* out         = (float*)d_out;

  const size_t nhwc_bytes = (size_t)N_IMGS * HW * CU_ * sizeof(uint32_t);
  const size_t need = nhwc_bytes + (size_t)R * sizeof(int);
  if (ws_size >= need) {
    uint32_t* nhwc16 = (uint32_t*)d_ws;
    int* perm = (int*)((char*)d_ws + nhwc_bytes);
    sort_rois_by_image<<<dim3(1), dim3(256), 0, stream>>>(rois, perm);
    dim3 tb(32, 8);
    dim3 tg(HW / 32, C / 64, N_IMGS);
    transpose_nchw_nhwc_bf16<<<tg, tb, 0, stream>>>(feats, nhwc16);
    roi_align_nhwc_bf16<<<dim3(R * NCT), dim3(512), 0, stream>>>(nhwc16, rois,
                                                                 perm, out);
  } else {
    roi_align_nchw<<<dim3(R * NCT), dim3(256), 0, stream>>>(feats, rois, out);
  }
}

// Round 11
// 81.028 us; speedup vs baseline: 4.6830x; 1.0516x over previous
//
#include <hip/hip_runtime.h>
#include <stdint.h>

#define N_IMGS 8
#define C 256
#define H 128
#define W 128
#define R 1024
#define HOUT 14
#define WOUT 14
#define NPOS 196          // HOUT*WOUT
#define HW (H * W)        // 16384
#define IMG_ELEMS (C * HW)
#define CTILE 32          // channels per block (roi kernel)
#define NCT (C / CTILE)   // 8 channel tiles per roi
#define TILE_ELEMS (CTILE * NPOS)  // 6272 floats, contiguous in output
#define CU_ (C / 2)       // uints per NHWC row (bf16-pair packed) = 128

typedef float f4_t __attribute__((ext_vector_type(4)));  // native vec for NT store
typedef float f2_t __attribute__((ext_vector_type(2)));  // for v_pk_fma_f32

__device__ __forceinline__ unsigned short f2bf(float f) {  // RTNE
  uint32_t u = __float_as_uint(f);
  uint32_t r = u + 0x7FFFu + ((u >> 16) & 1u);
  return (unsigned short)(r >> 16);
}

// ---------------------------------------------------------------------------
// Kernel 1: NCHW -> NHWC transpose with bf16 pack, with the roi-by-image
// counting sort folded into one extra grid.x slot (saves a serial ~3us
// launch). Per transpose block: 64ch x 32hw; loads coalesced 128B/instr;
// stores pack 2 channels/uint -> 128B/instr. ~BW-bound (201MB round trip).
// ---------------------------------------------------------------------------
__global__ __launch_bounds__(256) void transpose_nchw_nhwc_bf16(
    const float* __restrict__ in, uint32_t* __restrict__ out,
    const float* __restrict__ rois, int* __restrict__ perm) {
  const int tx = threadIdx.x;  // 0..31
  const int ty = threadIdx.y;  // 0..7

  if (blockIdx.x == HW / 32) {
    // Sorter slot: one block does the counting sort, siblings exit.
    if (blockIdx.y != 0 || blockIdx.z != 0) return;
    __shared__ int hist[N_IMGS];
    __shared__ int cursor[N_IMGS];
    const int tid = ty * 32 + tx;
    if (tid < N_IMGS) hist[tid] = 0;
    __syncthreads();
    for (int i = tid; i < R; i += 256) {
      atomicAdd(&hist[(int)rois[i * 5]], 1);
    }
    __syncthreads();
    if (tid == 0) {
      int acc = 0;
      for (int k = 0; k < N_IMGS; ++k) {
        cursor[k] = acc;
        acc += hist[k];
      }
    }
    __syncthreads();
    for (int i = tid; i < R; i += 256) {
      const int b = (int)rois[i * 5];
      const int pos = atomicAdd(&cursor[b], 1);
      perm[pos] = i;  // output is permutation-invariant per roi
    }
    return;
  }

  __shared__ float tile[64][33];
  const int n   = blockIdx.z;
  const int hw0 = blockIdx.x * 32;
  const int c0  = blockIdx.y * 64;
  const float* inp = in + (size_t)n * IMG_ELEMS;
  uint32_t* outp   = out + (size_t)n * (size_t)HW * CU_;

#pragma unroll
  for (int i = 0; i < 8; ++i) {
    int cc = ty + i * 8;  // 0..63
    tile[cc][tx] = inp[(size_t)(c0 + cc) * HW + hw0 + tx];
  }
  __syncthreads();
#pragma unroll
  for (int i = 0; i < 4; ++i) {
    int hh = ty + i * 8;  // 0..31
    const uint32_t lo = f2bf(tile[2 * tx + 0][hh]);
    const uint32_t hi = f2bf(tile[2 * tx + 1][hh]);
    outp[(size_t)(hw0 + hh) * CU_ + (c0 >> 1) + tx] = lo | (hi << 16);
  }
}

// ---------------------------------------------------------------------------
// Geometry precompute: offsets (pre-scaled by SCALE) and bilinear weights
// for all 196 positions of roi r into LDS.
// ---------------------------------------------------------------------------
template <int SCALE>
__device__ __forceinline__ void setup_roi(const float* __restrict__ rois,
                                          int r, int tid, int4* s_off,
                                          float4* s_w, int* s_n) {
  const float bf = rois[r * 5 + 0];
  const float x1 = rois[r * 5 + 1];
  const float y1 = rois[r * 5 + 2];
  const float x2 = rois[r * 5 + 3];
  const float y2 = rois[r * 5 + 4];
  if (tid == 0) *s_n = (int)bf;

  if (tid < NPOS) {
    const int ph = tid / WOUT;
    const int pw = tid - ph * WOUT;
    const float px_rel = (pw + 0.5f) / (float)WOUT;
    const float py_rel = (ph + 0.5f) / (float)HOUT;
    const float x_abs = px_rel * (x2 - x1) + x1;
    const float y_abs = py_rel * (y2 - y1) + y1;
    // rx = x_abs / W * 0.25 ; px = rx * W - 0.5  ==  x_abs * 0.25 - 0.5
    const float px = x_abs * 0.25f - 0.5f;
    const float py = y_abs * 0.25f - 0.5f;
    const float x0f = floorf(px);
    const float y0f = floorf(py);
    const float lx = px - x0f, ly = py - y0f;
    const float hx = 1.0f - lx, hy = 1.0f - ly;
    const int ix0 = (int)x0f;
    const int iy0 = (int)y0f;
    const int ix1 = ix0 + 1;
    const int iy1 = iy0 + 1;
    // Reference pads with zeros and clips into the pad -> OOB corners
    // contribute exactly 0. Reproduce by zeroing the weight.
    const bool vx0 = (ix0 >= 0) && (ix0 < W);
    const bool vx1 = (ix1 >= 0) && (ix1 < W);
    const bool vy0 = (iy0 >= 0) && (iy0 < H);
    const bool vy1 = (iy1 >= 0) && (iy1 < H);
    const int cx0 = min(max(ix0, 0), W - 1);
    const int cx1 = min(max(ix1, 0), W - 1);
    const int cy0 = min(max(iy0, 0), H - 1);
    const int cy1 = min(max(iy1, 0), H - 1);
    int4 o;
    o.x = (cy0 * W + cx0) * SCALE;
    o.y = (cy1 * W + cx0) * SCALE;
    o.z = (cy0 * W + cx1) * SCALE;
    o.w = (cy1 * W + cx1) * SCALE;
    float4 w4;
    w4.x = (vx0 && vy0) ? hx * hy : 0.0f;
    w4.y = (vx0 && vy1) ? hx * ly : 0.0f;
    w4.z = (vx1 && vy0) ? lx * hy : 0.0f;
    w4.w = (vx1 && vy1) ? lx * ly : 0.0f;
    s_off[tid] = o;
    s_w[tid]   = w4;
  }
}

// Unpack one bf16 pair (packed uint) to {lo, hi} floats as a float2 vector.
__device__ __forceinline__ f2_t up2(uint32_t q) {
  f2_t v;
  v.x = __uint_as_float(q << 16);
  v.y = __uint_as_float(q & 0xFFFF0000u);
  return v;
}

// Bilinear combine for 8 channels (4 bf16 pairs) of one position, float2
// vector math -> v_pk_fma_f32 (packed f32 FMA, CDNA) where available.
__device__ __forceinline__ void acc8(float* s_base, int p, uint4 a, uint4 b,
                                     uint4 c, uint4 d, float4 w) {
  const uint32_t qa[4] = {a.x, a.y, a.z, a.w};
  const uint32_t qb[4] = {b.x, b.y, b.z, b.w};
  const uint32_t qc[4] = {c.x, c.y, c.z, c.w};
  const uint32_t qd[4] = {d.x, d.y, d.z, d.w};
#pragma unroll
  for (int j = 0; j < 4; ++j) {
    f2_t acc = up2(qa[j]) * w.x;
    acc += up2(qb[j]) * w.y;
    acc += up2(qc[j]) * w.z;
    acc += up2(qd[j]) * w.w;
    s_base[(2 * j + 0) * NPOS + p] = acc.x;
    s_base[(2 * j + 1) * NPOS + p] = acc.y;
  }
}

// ---------------------------------------------------------------------------
// Kernel 2: RoI Align, bf16 NHWC input, uint4 = 8-channel gathers.
// 512 threads/block: roi = perm[bid>>3] (image-grouped), c0 = (bid&7)*32.
// Thread: channel octet lc8 = tid&3, position group g = tid>>2 in 0..127;
// positions p0 = g, p1 = 128+g (g<68). Image-grouped roi order + ctile==bid%8
// keeps each XCD's gather working set at ~1MB -> L2-resident. Results staged
// in LDS in exact output layout; nontemporal full-line writeout.
// ---------------------------------------------------------------------------
__global__ __launch_bounds__(512, 6) void roi_align_nhwc_bf16(
    const uint32_t* __restrict__ feats, const float* __restrict__ rois,
    const int* __restrict__ perm, float* __restrict__ out) {
  __shared__ int4   s_off[NPOS];   // uint-offsets, pre-scaled by CU_
  __shared__ float4 s_w[NPOS];
  __shared__ alignas(16) float s_res[TILE_ELEMS];  // [CTILE][NPOS] = out slice
  __shared__ int s_n;

  const int bid = blockIdx.x;
  const int r   = perm[bid >> 3];
  const int c0  = (bid & 7) * CTILE;
  const int tid = threadIdx.x;
  const int lc8 = tid & 3;   // channel octet within tile
  const int g   = tid >> 2;  // 0..127 position group

  setup_roi<CU_>(rois, r, tid, s_off, s_w, &s_n);
  __syncthreads();

  const uint32_t* base =
      feats + (size_t)s_n * (size_t)HW * CU_ + (c0 >> 1) + lc8 * 4;
  float* s_base = s_res + (lc8 * 8) * NPOS;

  const bool has1 = g < (NPOS - 128);  // g < 68
  const int p1 = 128 + g;

  // Issue all gathers (up to 8 uint4) before any consumption.
  const int4   o0 = s_off[g];
  const float4 w0 = s_w[g];
  uint4 A0 = *reinterpret_cast<const uint4*>(base + o0.x);
  uint4 B0 = *reinterpret_cast<const uint4*>(base + o0.y);
  uint4 C0 = *reinterpret_cast<const uint4*>(base + o0.z);
  uint4 D0 = *reinterpret_cast<const uint4*>(base + o0.w);
  if (has1) {
    const int4   o1 = s_off[p1];
    const float4 w1 = s_w[p1];
    const uint4 A1 = *reinterpret_cast<const uint4*>(base + o1.x);
    const uint4 B1 = *reinterpret_cast<const uint4*>(base + o1.y);
    const uint4 C1 = *reinterpret_cast<const uint4*>(base + o1.z);
    const uint4 D1 = *reinterpret_cast<const uint4*>(base + o1.w);
    acc8(s_base, g, A0, B0, C0, D0, w0);
    acc8(s_base, p1, A1, B1, C1, D1, w1);
  } else {
    acc8(s_base, g, A0, B0, C0, D0, w0);
  }
  __syncthreads();

  // Stream the tile out: contiguous 25088B, nontemporal 16B stores.
  const f4_t* s4 = reinterpret_cast<const f4_t*>(s_res);
  f4_t* out4 = reinterpret_cast<f4_t*>(out + ((size_t)r * C + c0) * NPOS);
#pragma unroll 1
  for (int i = tid; i < TILE_ELEMS / 4; i += 512) {
    __builtin_nontemporal_store(s4[i], &out4[i]);
  }
}

// ---------------------------------------------------------------------------
// Fallback (ws too small): scalar gathers straight from NCHW. Correct, slow.
// ---------------------------------------------------------------------------
__global__ __launch_bounds__(256, 4) void roi_align_nchw(
    const float* __restrict__ feats, const float* __restrict__ rois,
    float* __restrict__ out) {
  __shared__ int4   s_off[NPOS];
  __shared__ float4 s_w[NPOS];
  __shared__ alignas(16) float s_res[TILE_ELEMS];
  __shared__ int s_n;

  const int bid = blockIdx.x;
  const int r   = bid >> 3;
  const int c0  = (bid & 7) * CTILE;
  const int tid = threadIdx.x;
  const int lc  = tid & (CTILE - 1);
  const int g   = tid >> 5;  // 0..7

  setup_roi<1>(rois, r, tid, s_off, s_w, &s_n);
  __syncthreads();

  const float* base = feats + (size_t)s_n * IMG_ELEMS + (size_t)(c0 + lc) * HW;
  float* s_row = s_res + lc * NPOS;
#pragma unroll 1
  for (int p = g; p < NPOS; p += 8) {
    const int4   o = s_off[p];
    const float4 w = s_w[p];
    s_row[p] = base[o.x] * w.x + base[o.y] * w.y + base[o.z] * w.z +
               base[o.w] * w.w;
  }
  __syncthreads();

  const float4* s4 = reinterpret_cast<const float4*>(s_res);
  float4* out4 = reinterpret_cast<float4*>(out + ((size_t)r * C + c0) * NPOS);
#pragma unroll 1
  for (int i = tid; i < TILE_ELEMS / 4; i += 256) {
    out4[i] = s4[i];
  }
}

extern "C" void kernel_launch(void* const* d_in, const int* in_sizes, int n_in,
                              void* d_out, int out_size, void* d_ws,
                              size_t ws_size, hipStream_t stream) {
  const float* feats = (const float*)d_in[0];
  const float* rois  = (const float*)d_in[1];
  float* out         = (float*)d_out;

  const size_t nhwc_bytes = (size_t)N_IMGS * HW * CU_ * sizeof(uint32_t);
  const size_t need = nhwc_bytes + (size_t)R * sizeof(int);
  if (ws_size >= need) {
    uint32_t* nhwc16 = (uint32_t*)d_ws;
    int* perm = (int*)((char*)d_ws + nhwc_bytes);
    dim3 tb(32, 8);
    dim3 tg(HW / 32 + 1, C / 64, N_IMGS);  // +1 slot hosts the roi sort
    transpose_nchw_nhwc_bf16<<<tg, tb, 0, stream>>>(feats, nhwc16, rois, perm);
    roi_align_nhwc_bf16<<<dim3(R * NCT), dim3(512), 0, stream>>>(nhwc16, rois,
                                                                 perm, out);
  } else {
    roi_align_nchw<<<dim3(R * NCT), dim3(256), 0, stream>>>(feats, rois, out);
  }
}